// Round 2
// baseline (88.197 us; speedup 1.0000x reference)
//
#include <hip/hip_runtime.h>
#include <hip/hip_bf16.h>
#include <stdint.h>
#include <math.h>

// Problem constants
#define VOCAB 1000000
#define D 128
#define NROWS 16384
#define NSAMP 8192
#define SSPLIT 16                      // flash: S split across 16 block groups
#define K1F 28.853900817779268f        // (1/TEMP)*log2(e) = 20*log2(e)
#define LOG2EF 1.4426950408889634f

// ws layout (bytes)
#define XF_OFF 0u                      // N*D bf16 = 4 MB, fragment-major, pre-scaled by K1F
#define EF_OFF 4194304u                // S*D bf16 = 2 MB, fragment-major
#define PL_OFF 6291456u                // pos_logit fp32 [N]
#define PS_OFF 6356992u                // psum fp32 [SSPLIT][N] = 1 MB
#define FP_OFF 7405568u                // finish partials [64][2]

typedef __attribute__((ext_vector_type(8))) __bf16 bf16x8;
typedef __attribute__((ext_vector_type(16))) float f32x16;

#if __has_builtin(__builtin_amdgcn_exp2f)
#define EXP2(x) __builtin_amdgcn_exp2f(x)
#else
#define EXP2(x) exp2f(x)
#endif

__device__ __forceinline__ void gl_lds16(const void* g, void* l) {
  __builtin_amdgcn_global_load_lds(
      (const __attribute__((address_space(1))) unsigned int*)g,
      (__attribute__((address_space(3))) unsigned int*)l, 16, 0, 0);
}

__device__ __forceinline__ float wave_sum(float v) {
#pragma unroll
  for (int o = 1; o < 64; o <<= 1) v += __shfl_xor(v, o);
  return v;
}

// exp2 each of 16 fp32 and tree-sum (short dependent chains).
__device__ __forceinline__ float expsum16(const f32x16& c) {
  float e[16];
#pragma unroll
  for (int r = 0; r < 16; ++r) e[r] = EXP2(c[r]);
#pragma unroll
  for (int s = 8; s; s >>= 1)
#pragma unroll
    for (int r = 0; r < s; ++r) e[r] += e[r + s];
  return e[0];
}

// Merged prep: blocks [0,4096) handle X rows (normalize, pre-scale by K1F,
// fragment-major bf16 store, fp32 pos logit); blocks [4096,6144) handle E rows.
__global__ void prep_kernel(const float* __restrict__ x,
                            const int* __restrict__ tgt,
                            const int* __restrict__ nid,
                            const float* __restrict__ proj,
                            __bf16* __restrict__ xf,
                            __bf16* __restrict__ ef,
                            float* __restrict__ pl) {
  const int wave = threadIdx.x >> 6, lane = threadIdx.x & 63;
  const int d = lane * 2;
  const int kk = d >> 4, sub = (d & 15) >> 3, j = d & 7;
  if (blockIdx.x < 4096) {
    const int n = blockIdx.x * 4 + wave;
    const float2 xr = *reinterpret_cast<const float2*>(x + (size_t)n * D + lane * 2);
    const float rnx = 1.f / (sqrtf(wave_sum(xr.x * xr.x + xr.y * xr.y)) + 1e-12f);
    const int t = tgt[n];
    const int tg = t < 0 ? 0 : (t > VOCAB - 1 ? VOCAB - 1 : t);
    const float2 pr = *reinterpret_cast<const float2*>(proj + (size_t)tg * D + lane * 2);
    const float rnp = 1.f / (sqrtf(wave_sum(pr.x * pr.x + pr.y * pr.y)) + 1e-12f);
    const float dt = wave_sum(xr.x * pr.x + xr.y * pr.y);
    if (lane == 0) pl[n] = dt * rnx * rnp * 20.0f;  // /TEMP, exact fp32
    const int tile = n >> 5, lt = (sub << 5) | (n & 31);
    __bf16* dst = xf + ((((size_t)tile * 8 + kk) * 64 + lt) * 8 + j);
    const float s = rnx * K1F;  // fold logit scale (in log2 base) into X
    dst[0] = (__bf16)(xr.x * s);
    dst[1] = (__bf16)(xr.y * s);
  } else {
    const int s = (blockIdx.x - 4096) * 4 + wave;
    const int id = nid[s];
    const float2 er = *reinterpret_cast<const float2*>(proj + (size_t)id * D + lane * 2);
    const float rn = 1.f / (sqrtf(wave_sum(er.x * er.x + er.y * er.y)) + 1e-12f);
    const int tile = s >> 5, lt = (sub << 5) | (s & 31);
    __bf16* dst = ef + ((((size_t)tile * 8 + kk) * 64 + lt) * 8 + j);
    dst[0] = (__bf16)(er.x * rn);
    dst[1] = (__bf16)(er.y * rn);
  }
}

// Flash kernel: block = 512 rows of X (8 waves x 64 cols), loops over a 512-s
// slice of E in 8 64-s supertiles (double-buffered LDS via global_load_lds).
// MFMA yields logit*log2e directly; accumulates sum_s exp2(.) into psum[ss][n].
__global__ __launch_bounds__(512, 4) void flash_kernel(
    const __bf16* __restrict__ xf, const __bf16* __restrict__ ef,
    float* __restrict__ psum) {
  __shared__ __align__(16) char lds[2][16384];
  const int tid = threadIdx.x, wave = tid >> 6, lane = tid & 63;
  const int nb = blockIdx.x & 31, ss = blockIdx.x >> 5;

  // B fragments (X): 2 n-frags x 8 k-steps, straight from global (frag-major)
  bf16x8 bq[2][8];
#pragma unroll
  for (int nf = 0; nf < 2; ++nf) {
    const __bf16* p = xf + ((size_t)(nb * 16 + wave * 2 + nf) * 4096) + lane * 8;
#pragma unroll
    for (int kk = 0; kk < 8; ++kk)
      bq[nf][kk] = *reinterpret_cast<const bf16x8*>(p + kk * 512);
  }

  const char* esrc = reinterpret_cast<const char*>(ef) + (size_t)ss * 131072;
  float acc0 = 0.f, acc1 = 0.f;

  {  // stage supertile 0
    const char* g = esrc + wave * 1024 + lane * 16;
    char* l = &lds[0][0] + wave * 1024;
    gl_lds16(g, l);
    gl_lds16(g + 8192, l + 8192);
  }
  __syncthreads();

  for (int st = 0; st < 8; ++st) {
    if (st < 7) {  // prefetch next supertile into the other buffer
      const char* g = esrc + (size_t)(st + 1) * 16384 + wave * 1024 + lane * 16;
      char* l = &lds[(st + 1) & 1][0] + wave * 1024;
      gl_lds16(g, l);
      gl_lds16(g + 8192, l + 8192);
    }
    const char* cb = &lds[st & 1][0];
#pragma unroll
    for (int tt = 0; tt < 2; ++tt) {
      f32x16 c0, c1;
#pragma unroll
      for (int r = 0; r < 16; ++r) { c0[r] = 0.f; c1[r] = 0.f; }
      const char* ab = cb + tt * 8192 + lane * 16;
#pragma unroll
      for (int kk = 0; kk < 8; ++kk) {
        bf16x8 a = *reinterpret_cast<const bf16x8*>(ab + kk * 1024);
        c0 = __builtin_amdgcn_mfma_f32_32x32x16_bf16(a, bq[0][kk], c0, 0, 0, 0);
        c1 = __builtin_amdgcn_mfma_f32_32x32x16_bf16(a, bq[1][kk], c1, 0, 0, 0);
      }
      acc0 += expsum16(c0);
      acc1 += expsum16(c1);
    }
    __syncthreads();
  }

  // lanes l and l+32 hold different s-rows of the same column n: combine.
  acc0 += __shfl_xor(acc0, 32);
  acc1 += __shfl_xor(acc1, 32);
  if (lane < 32) {
    const int nbase = nb * 512 + wave * 64;
    psum[(size_t)ss * NROWS + nbase + lane] = acc0;
    psum[(size_t)ss * NROWS + nbase + 32 + lane] = acc1;
  }
}

// Per-row CE + weighted partial sums (deterministic two-stage reduction).
__global__ void finish_kernel(const float* __restrict__ psum,
                              const float* __restrict__ pl,
                              const int* __restrict__ tgt,
                              const float* __restrict__ wts,
                              float* __restrict__ fin) {
  const int n = blockIdx.x * 256 + threadIdx.x;
  float tot = 0.f;
#pragma unroll
  for (int s = 0; s < SSPLIT; ++s) tot += psum[(size_t)s * NROWS + n];
  const float p = pl[n];
  tot += EXP2(p * LOG2EF);             // + exp(pos_logit), unshifted
  const float ce = logf(tot) - p;      // logZ - pos_logit
  const float w = wts[n] * (tgt[n] != -100 ? 1.f : 0.f);
  float a = wave_sum(ce * w);
  float b = wave_sum(w);
  __shared__ float sa[4], sb[4];
  const int wave = threadIdx.x >> 6, lane = threadIdx.x & 63;
  if (lane == 0) { sa[wave] = a; sb[wave] = b; }
  __syncthreads();
  if (threadIdx.x == 0) {
    fin[blockIdx.x * 2] = sa[0] + sa[1] + sa[2] + sa[3];
    fin[blockIdx.x * 2 + 1] = sb[0] + sb[1] + sb[2] + sb[3];
  }
}

__global__ void final_kernel(const float* __restrict__ fin, float* __restrict__ out) {
  const int l = threadIdx.x;
  float a = wave_sum(fin[l * 2]);
  float b = wave_sum(fin[l * 2 + 1]);
  if (l == 0) out[0] = a / fmaxf(b, 1e-12f);
}

extern "C" void kernel_launch(void* const* d_in, const int* in_sizes, int n_in,
                              void* d_out, int out_size, void* d_ws, size_t ws_size,
                              hipStream_t stream) {
  const float* x    = (const float*)d_in[0];
  const int*   tgt  = (const int*)d_in[1];
  const int*   nid  = (const int*)d_in[2];
  const float* wts  = (const float*)d_in[3];
  const float* proj = (const float*)d_in[4];
  float* out = (float*)d_out;
  char* ws = (char*)d_ws;
  __bf16* xf = (__bf16*)(ws + XF_OFF);
  __bf16* ef = (__bf16*)(ws + EF_OFF);
  float* pl   = (float*)(ws + PL_OFF);
  float* psum = (float*)(ws + PS_OFF);
  float* fin  = (float*)(ws + FP_OFF);

  hipLaunchKernelGGL(prep_kernel, dim3(4096 + 2048), dim3(256), 0, stream,
                     x, tgt, nid, proj, xf, ef, pl);
  hipLaunchKernelGGL(flash_kernel, dim3(32 * SSPLIT), dim3(512), 0, stream,
                     xf, ef, psum);
  hipLaunchKernelGGL(finish_kernel, dim3(NROWS / 256), dim3(256), 0, stream,
                     psum, pl, tgt, wts, fin);
  hipLaunchKernelGGL(final_kernel, dim3(1), dim3(64), 0, stream, fin, out);
}

// Round 3
// 52.209 us; speedup vs baseline: 1.6893x; 1.6893x over previous
//
#include <hip/hip_runtime.h>
#include <hip/hip_bf16.h>
#include <stdint.h>
#include <math.h>

// Problem constants
#define VOCAB 1000000
#define D 128
#define NROWS 16384
#define NSAMP 8192
#define SSPLIT 8                       // flash: S split across 8 block groups
#define K1F 28.853900817779268f        // (1/TEMP)*log2(e) = 20*log2(e)
#define LOG2EF 1.4426950408889634f

// ws layout (bytes)
#define XF_OFF 0u                      // N*D bf16 = 4 MB, fragment-major, pre-scaled by K1F
#define EF_OFF 4194304u                // S*D bf16 = 2 MB, fragment-major
#define PL_OFF 6291456u                // pos_logit fp32 [N]
#define PS_OFF 6356992u                // psum fp32 [SSPLIT][N] = 512 KB
#define FP_OFF 7405568u                // finish partials [64][2]

typedef __attribute__((ext_vector_type(8))) __bf16 bf16x8;
typedef __attribute__((ext_vector_type(16))) float f32x16;

#if __has_builtin(__builtin_amdgcn_exp2f)
#define EXP2(x) __builtin_amdgcn_exp2f(x)
#else
#define EXP2(x) exp2f(x)
#endif

__device__ __forceinline__ void gl_lds16(const void* g, void* l) {
  __builtin_amdgcn_global_load_lds(
      (const __attribute__((address_space(1))) unsigned int*)g,
      (__attribute__((address_space(3))) unsigned int*)l, 16, 0, 0);
}

__device__ __forceinline__ float wave_sum(float v) {
#pragma unroll
  for (int o = 1; o < 64; o <<= 1) v += __shfl_xor(v, o);
  return v;
}

// exp2 each of 16 fp32 and tree-sum (short dependent chains).
__device__ __forceinline__ float expsum16(const f32x16& c) {
  float e[16];
#pragma unroll
  for (int r = 0; r < 16; ++r) e[r] = EXP2(c[r]);
#pragma unroll
  for (int s = 8; s; s >>= 1)
#pragma unroll
    for (int r = 0; r < s; ++r) e[r] += e[r + s];
  return e[0];
}

// Merged prep: blocks [0,4096) handle X rows (normalize, pre-scale by K1F,
// fragment-major bf16 store, fp32 pos logit); blocks [4096,6144) handle E rows.
__global__ void prep_kernel(const float* __restrict__ x,
                            const int* __restrict__ tgt,
                            const int* __restrict__ nid,
                            const float* __restrict__ proj,
                            __bf16* __restrict__ xf,
                            __bf16* __restrict__ ef,
                            float* __restrict__ pl) {
  const int wave = threadIdx.x >> 6, lane = threadIdx.x & 63;
  const int d = lane * 2;
  const int kk = d >> 4, sub = (d & 15) >> 3, j = d & 7;
  if (blockIdx.x < 4096) {
    const int n = blockIdx.x * 4 + wave;
    const float2 xr = *reinterpret_cast<const float2*>(x + (size_t)n * D + lane * 2);
    const float rnx = 1.f / (sqrtf(wave_sum(xr.x * xr.x + xr.y * xr.y)) + 1e-12f);
    const int t = tgt[n];
    const int tg = t < 0 ? 0 : (t > VOCAB - 1 ? VOCAB - 1 : t);
    const float2 pr = *reinterpret_cast<const float2*>(proj + (size_t)tg * D + lane * 2);
    const float rnp = 1.f / (sqrtf(wave_sum(pr.x * pr.x + pr.y * pr.y)) + 1e-12f);
    const float dt = wave_sum(xr.x * pr.x + xr.y * pr.y);
    if (lane == 0) pl[n] = dt * rnx * rnp * 20.0f;  // /TEMP, exact fp32
    const int tile = n >> 5, lt = (sub << 5) | (n & 31);
    __bf16* dst = xf + ((((size_t)tile * 8 + kk) * 64 + lt) * 8 + j);
    const float s = rnx * K1F;  // fold logit scale (in log2 base) into X
    dst[0] = (__bf16)(xr.x * s);
    dst[1] = (__bf16)(xr.y * s);
  } else {
    const int s = (blockIdx.x - 4096) * 4 + wave;
    const int id = nid[s];
    const float2 er = *reinterpret_cast<const float2*>(proj + (size_t)id * D + lane * 2);
    const float rn = 1.f / (sqrtf(wave_sum(er.x * er.x + er.y * er.y)) + 1e-12f);
    const int tile = s >> 5, lt = (sub << 5) | (s & 31);
    __bf16* dst = ef + ((((size_t)tile * 8 + kk) * 64 + lt) * 8 + j);
    dst[0] = (__bf16)(er.x * rn);
    dst[1] = (__bf16)(er.y * rn);
  }
}

// Flash kernel: block = 256 rows of X (8 waves x 32 cols each), loops over a
// 1024-s slice of E in 16 64-s supertiles (double-buffered LDS staging via
// global_load_lds). MFMA yields logit*log2e directly; accumulates
// sum_s exp2(.) into psum[ss][n]. ~95 VGPR/wave -> 4 waves/SIMD, no spill.
__global__ __launch_bounds__(512, 4) void flash_kernel(
    const __bf16* __restrict__ xf, const __bf16* __restrict__ ef,
    float* __restrict__ psum) {
  __shared__ __align__(16) char lds[2][16384];
  const int tid = threadIdx.x, wave = tid >> 6, lane = tid & 63;
  const int nb = blockIdx.x & 63, ss = blockIdx.x >> 6;

  // B fragments (X): 1 n-frag (32 rows) x 8 k-steps, straight from global.
  bf16x8 bq[8];
  {
    const __bf16* p = xf + ((size_t)(nb * 8 + wave) * 4096) + lane * 8;
#pragma unroll
    for (int kk = 0; kk < 8; ++kk)
      bq[kk] = *reinterpret_cast<const bf16x8*>(p + kk * 512);
  }

  const char* esrc = reinterpret_cast<const char*>(ef) + (size_t)ss * 262144;
  float acc = 0.f;

  {  // stage supertile 0
    const char* g = esrc + wave * 1024 + lane * 16;
    char* l = &lds[0][0] + wave * 1024;
    gl_lds16(g, l);
    gl_lds16(g + 8192, l + 8192);
  }
  __syncthreads();

  for (int st = 0; st < 16; ++st) {
    if (st < 15) {  // prefetch next supertile into the other buffer
      const char* g = esrc + (size_t)(st + 1) * 16384 + wave * 1024 + lane * 16;
      char* l = &lds[(st + 1) & 1][0] + wave * 1024;
      gl_lds16(g, l);
      gl_lds16(g + 8192, l + 8192);
    }
    const char* cb = &lds[st & 1][0];
#pragma unroll
    for (int tt = 0; tt < 2; ++tt) {
      f32x16 c;
#pragma unroll
      for (int r = 0; r < 16; ++r) c[r] = 0.f;
      const char* ab = cb + tt * 8192 + lane * 16;
#pragma unroll
      for (int kk = 0; kk < 8; ++kk) {
        bf16x8 a = *reinterpret_cast<const bf16x8*>(ab + kk * 1024);
        c = __builtin_amdgcn_mfma_f32_32x32x16_bf16(a, bq[kk], c, 0, 0, 0);
      }
      acc += expsum16(c);
    }
    __syncthreads();
  }

  // lanes l and l+32 hold different s-rows of the same column n: combine.
  acc += __shfl_xor(acc, 32);
  if (lane < 32) {
    const int nbase = nb * 256 + wave * 32;
    psum[(size_t)ss * NROWS + nbase + lane] = acc;
  }
}

// Per-row CE + weighted partial sums (deterministic two-stage reduction).
__global__ void finish_kernel(const float* __restrict__ psum,
                              const float* __restrict__ pl,
                              const int* __restrict__ tgt,
                              const float* __restrict__ wts,
                              float* __restrict__ fin) {
  const int n = blockIdx.x * 256 + threadIdx.x;
  float tot = 0.f;
#pragma unroll
  for (int s = 0; s < SSPLIT; ++s) tot += psum[(size_t)s * NROWS + n];
  const float p = pl[n];
  tot += EXP2(p * LOG2EF);             // + exp(pos_logit), unshifted
  const float ce = logf(tot) - p;      // logZ - pos_logit
  const float w = wts[n] * (tgt[n] != -100 ? 1.f : 0.f);
  float a = wave_sum(ce * w);
  float b = wave_sum(w);
  __shared__ float sa[4], sb[4];
  const int wave = threadIdx.x >> 6, lane = threadIdx.x & 63;
  if (lane == 0) { sa[wave] = a; sb[wave] = b; }
  __syncthreads();
  if (threadIdx.x == 0) {
    fin[blockIdx.x * 2] = sa[0] + sa[1] + sa[2] + sa[3];
    fin[blockIdx.x * 2 + 1] = sb[0] + sb[1] + sb[2] + sb[3];
  }
}

__global__ void final_kernel(const float* __restrict__ fin, float* __restrict__ out) {
  const int l = threadIdx.x;
  float a = wave_sum(fin[l * 2]);
  float b = wave_sum(fin[l * 2 + 1]);
  if (l == 0) out[0] = a / fmaxf(b, 1e-12f);
}

extern "C" void kernel_launch(void* const* d_in, const int* in_sizes, int n_in,
                              void* d_out, int out_size, void* d_ws, size_t ws_size,
                              hipStream_t stream) {
  const float* x    = (const float*)d_in[0];
  const int*   tgt  = (const int*)d_in[1];
  const int*   nid  = (const int*)d_in[2];
  const float* wts  = (const float*)d_in[3];
  const float* proj = (const float*)d_in[4];
  float* out = (float*)d_out;
  char* ws = (char*)d_ws;
  __bf16* xf = (__bf16*)(ws + XF_OFF);
  __bf16* ef = (__bf16*)(ws + EF_OFF);
  float* pl   = (float*)(ws + PL_OFF);
  float* psum = (float*)(ws + PS_OFF);
  float* fin  = (float*)(ws + FP_OFF);

  hipLaunchKernelGGL(prep_kernel, dim3(4096 + 2048), dim3(256), 0, stream,
                     x, tgt, nid, proj, xf, ef, pl);
  hipLaunchKernelGGL(flash_kernel, dim3(64 * SSPLIT), dim3(512), 0, stream,
                     xf, ef, psum);
  hipLaunchKernelGGL(finish_kernel, dim3(NROWS / 256), dim3(256), 0, stream,
                     psum, pl, tgt, wts, fin);
  hipLaunchKernelGGL(final_kernel, dim3(1), dim3(64), 0, stream, fin, out);
}